// Round 6
// baseline (18.738 us; speedup 1.0000x reference)
//
#include <hip/hip_runtime.h>

#define SDF_THR 5e-5f
#define TRACE_ITERS 10
#define N_STEPS 100
#define N_ROOTFIND 8

// raw v_sqrt_f32 (~1 ulp) — avoids the IEEE fixup sequence on the critical path
__device__ __forceinline__ float fast_sqrtf(float x) {
#if __has_builtin(__builtin_amdgcn_sqrtf)
    return __builtin_amdgcn_sqrtf(x);
#else
    return sqrtf(x);
#endif
}

// correctly-rounded k/99.0f (Markstein 2-fma refinement); constant-folds for literal k
__device__ __forceinline__ float div99(int k) {
    const float c = 1.0f / 99.0f;
    float fk = (float)k;
    float t0 = fk * c;
    float e  = fmaf(t0, -99.0f, fk);
    return fmaf(e, c, t0);
}

// sdf(cam + a*ray) with |ray|=1:  q(a) = a^2 + 2a*rcd + cam2
__device__ __forceinline__ float sdfq(float a, float trcd, float cam2) {
    float q = fmaf(a, a + trcd, cam2);
    return fast_sqrtf(fmaxf(q, 0.0f)) - 1.0f;
}

// 2 rays per thread: ILP-4 in the trace loop (2 rays x {start,end} chains).
// Math per ray is bit-identical to the round-5 kernel.
__global__ __launch_bounds__(256) void raytrace2_kernel(
    const float* __restrict__ cam, const float* __restrict__ ray,
    float* __restrict__ out, int N, int R)
{
    int half = (R + 1) >> 1;
    int t = blockIdx.x * blockDim.x + threadIdx.x;
    if (t >= half) return;

    int  g[2]     = { t, t + half };
    bool valid[2] = { true, g[1] < R };
    g[1] = valid[1] ? g[1] : (R - 1);          // clamp for safe loads; masked below

    float cx[2], cy[2], cz[2], rx[2], ry[2], rz[2];
    float rcd[2], cam2[2], trcd[2];
    #pragma unroll
    for (int r = 0; r < 2; ++r) {
        int b = g[r] / N;
        cx[r] = cam[b * 3 + 0]; cy[r] = cam[b * 3 + 1]; cz[r] = cam[b * 3 + 2];
        rx[r] = ray[(size_t)g[r] * 3 + 0];
        ry[r] = ray[(size_t)g[r] * 3 + 1];
        rz[r] = ray[(size_t)g[r] * 3 + 2];
        rcd[r]  = rx[r] * cx[r] + ry[r] * cy[r] + rz[r] * cz[r];
        cam2[r] = cx[r] * cx[r] + cy[r] * cy[r] + cz[r] * cz[r];
        trcd[r] = rcd[r] + rcd[r];
    }

    bool  unf_s[2], unf_e[2];
    float acc_s[2], acc_e[2], next_s[2], next_e[2];
    #pragma unroll
    for (int r = 0; r < 2; ++r) {
        // sphere intersections (OBJ_R = 5); one-time sqrt kept correctly rounded
        float under = rcd[r] * rcd[r] - (cam2[r] - 25.0f);
        bool  m0 = under > 0.0f;
        float sq = sqrtf(m0 ? under : 1.0f);
        float nearv = m0 ? fmaxf(-sq - rcd[r], 0.0f) : 0.0f;
        float farv  = m0 ? fmaxf( sq - rcd[r], 0.0f) : 0.0f;
        unf_s[r] = m0; unf_e[r] = m0;
        acc_s[r] = nearv; acc_e[r] = farv;
        next_s[r] = unf_s[r] ? sdfq(acc_s[r], trcd[r], cam2[r]) : 0.0f;
        next_e[r] = unf_e[r] ? sdfq(acc_e[r], trcd[r], cam2[r]) : 0.0f;
    }

    #pragma unroll 1
    for (int i = 0; i < TRACE_ITERS; ++i) {
        #pragma unroll
        for (int r = 0; r < 2; ++r) {
            float cur_s = unf_s[r] ? next_s[r] : 0.0f;
            cur_s = (cur_s <= SDF_THR) ? 0.0f : cur_s;
            float cur_e = unf_e[r] ? next_e[r] : 0.0f;
            cur_e = (cur_e <= SDF_THR) ? 0.0f : cur_e;
            unf_s[r] = unf_s[r] && (cur_s > SDF_THR);
            unf_e[r] = unf_e[r] && (cur_e > SDF_THR);
            acc_s[r] += cur_s;
            acc_e[r] -= cur_e;
            next_s[r] = unf_s[r] ? sdfq(acc_s[r], trcd[r], cam2[r]) : 0.0f;
            next_e[r] = unf_e[r] ? sdfq(acc_e[r], trcd[r], cam2[r]) : 0.0f;
            bool np_s = (next_s[r] < 0.0f) || (rcd[r] + acc_s[r] > 0.0f);
            bool np_e = (next_e[r] < 0.0f) || (rcd[r] + acc_e[r] < 0.0f);
            // branchless line-search back-off (bit-exact: when !np the recompute
            // reproduces the same value and the select keeps the old one)
            float as2 = acc_s[r] - 0.9f * cur_s;
            float ae2 = acc_e[r] + 0.9f * cur_e;
            acc_s[r] = np_s ? as2 : acc_s[r];
            acc_e[r] = np_e ? ae2 : acc_e[r];
            float ns2 = sdfq(acc_s[r], trcd[r], cam2[r]);
            float ne2 = sdfq(acc_e[r], trcd[r], cam2[r]);
            next_s[r] = np_s ? ns2 : next_s[r];
            next_e[r] = np_e ? ne2 : next_e[r];
            bool lt = acc_s[r] < acc_e[r];
            unf_s[r] = unf_s[r] && lt;
            unf_e[r] = unf_e[r] && lt;
        }
        if (!__any(unf_s[0] || unf_e[0] || unf_s[1] || unf_e[1])) break;
    }

    #pragma unroll
    for (int r = 0; r < 2; ++r) {
        // final mask refresh
        float cur_s = unf_s[r] ? next_s[r] : 0.0f;
        cur_s = (cur_s <= SDF_THR) ? 0.0f : cur_s;
        unf_s[r] = unf_s[r] && (cur_s > SDF_THR);

        bool  out_m = acc_s[r] < acc_e[r];
        float out_d = acc_s[r];

        if (unf_s[r]) {
            // sampler: decisions on q(z) vs 1; 4 independent accumulator chains
            float smin = acc_s[r], dzr = acc_e[r] - acc_s[r];

            float qmin[4] = {3.4e38f, 3.4e38f, 3.4e38f, 3.4e38f};
            float fkq[4]  = {0.0f, 0.0f, 0.0f, 0.0f};
            float fneg[4] = {1e9f, 1e9f, 1e9f, 1e9f};

            #pragma unroll
            for (int k = 0; k < N_STEPS; ++k) {
                int j = k & 3;
                float z = fmaf(div99(k), dzr, smin);   // div99(k) folds to a constant
                float q = fmaf(z, z + trcd[r], cam2[r]);
                float fk = (float)k;
                fneg[j] = fminf(fneg[j], (q < 1.0f) ? fk : 1e9f);
                if (q < qmin[j]) { qmin[j] = q; fkq[j] = fk; }
            }

            float kneg_f = fminf(fminf(fneg[0], fneg[1]), fminf(fneg[2], fneg[3]));
            float bq = qmin[0], bk = fkq[0];
            #pragma unroll
            for (int j = 1; j < 4; ++j) {
                bool better = (qmin[j] < bq) || ((qmin[j] == bq) && (fkq[j] < bk));
                bq = better ? qmin[j] : bq;
                bk = better ? fkq[j]  : bk;
            }

            if (kneg_f < 1e8f) {
                // bisection between samples kneg-1 and kneg
                int kneg = (int)kneg_f;
                int klo  = (kneg - 1 > 0) ? (kneg - 1) : 0;
                float lo = fmaf(div99(klo),  dzr, smin);
                float hi = fmaf(div99(kneg), dzr, smin);
                #pragma unroll
                for (int it = 0; it < N_ROOTFIND; ++it) {
                    float mid = 0.5f * (lo + hi);
                    float qm  = fmaf(mid, mid + trcd[r], cam2[r]);
                    bool go_lo = qm > 1.0f;            // sdf(mid) > 0
                    lo = go_lo ? mid : lo;
                    hi = go_lo ? hi : mid;
                }
                out_d = 0.5f * (lo + hi);
                out_m = true;
            } else {
                out_d = fmaf(div99((int)bk), dzr, smin);
                out_m = false;
            }
        }

        if (valid[r]) {
            out[(size_t)g[r] * 3 + 0] = fmaf(out_d, rx[r], cx[r]);
            out[(size_t)g[r] * 3 + 1] = fmaf(out_d, ry[r], cy[r]);
            out[(size_t)g[r] * 3 + 2] = fmaf(out_d, rz[r], cz[r]);
            out[(size_t)R * 3 + g[r]] = out_m ? 1.0f : 0.0f;
            out[(size_t)R * 4 + g[r]] = out_d;
        }
    }
}

extern "C" void kernel_launch(void* const* d_in, const int* in_sizes, int n_in,
                              void* d_out, int out_size, void* d_ws, size_t ws_size,
                              hipStream_t stream) {
    const float* cam = (const float*)d_in[0];
    const float* ray = (const float*)d_in[1];
    int B = in_sizes[0] / 3;
    int R = in_sizes[1] / 3;
    int N = R / B;
    int half = (R + 1) >> 1;
    int threads = 256;
    int blocks = (half + threads - 1) / threads;
    raytrace2_kernel<<<blocks, threads, 0, stream>>>(cam, ray, (float*)d_out, N, R);
}

// Round 7
// 16.251 us; speedup vs baseline: 1.1530x; 1.1530x over previous
//
#include <hip/hip_runtime.h>

#define SDF_THR 5e-5f
#define TRACE_ITERS 10
#define N_STEPS 100
#define N_ROOTFIND 8
#define QGUARD 1e-5f

// raw v_sqrt_f32 (~1 ulp) — avoids the IEEE fixup sequence on the critical path
__device__ __forceinline__ float fast_sqrtf(float x) {
#if __has_builtin(__builtin_amdgcn_sqrtf)
    return __builtin_amdgcn_sqrtf(x);
#else
    return sqrtf(x);
#endif
}

// correctly-rounded k/99.0f (Markstein 2-fma refinement); identical value whether
// constant-folded (literal k) or evaluated at runtime — keeps z_k bit-identical.
__device__ __forceinline__ float div99(int k) {
    const float c = 1.0f / 99.0f;
    float fk = (float)k;
    float t0 = fk * c;
    float e  = fmaf(t0, -99.0f, fk);
    return fmaf(e, c, t0);
}

__device__ __forceinline__ float zq(int k, float dzr, float smin) {
    return fmaf(div99(k), dzr, smin);
}
__device__ __forceinline__ float qat(float z, float trcd, float cam2) {
    return fmaf(z, z + trcd, cam2);
}

// sdf(cam + a*ray) with |ray|=1:  q(a) = a^2 + 2a*rcd + cam2
__device__ __forceinline__ float sdfq(float a, float trcd, float cam2) {
    return fast_sqrtf(fmaxf(qat(a, trcd, cam2), 0.0f)) - 1.0f;
}

__global__ __launch_bounds__(256) void raytrace_kernel(
    const float* __restrict__ cam, const float* __restrict__ ray,
    float* __restrict__ out, int N, int R)
{
    int gid = blockIdx.x * blockDim.x + threadIdx.x;
    if (gid >= R) return;
    int b = gid / N;

    float cx = cam[b * 3 + 0], cy = cam[b * 3 + 1], cz = cam[b * 3 + 2];
    float rx = ray[(size_t)gid * 3 + 0], ry = ray[(size_t)gid * 3 + 1], rz = ray[(size_t)gid * 3 + 2];

    float rcd  = rx * cx + ry * cy + rz * cz;
    float cam2 = cx * cx + cy * cy + cz * cz;
    float trcd = rcd + rcd;

    // ---- sphere intersections (OBJ_R = 5); one-time sqrt kept correctly rounded ----
    float under = rcd * rcd - (cam2 - 25.0f);
    bool  m0 = under > 0.0f;
    float sq = sqrtf(m0 ? under : 1.0f);
    float nearv = m0 ? fmaxf(-sq - rcd, 0.0f) : 0.0f;
    float farv  = m0 ? fmaxf( sq - rcd, 0.0f) : 0.0f;

    // ---- sphere tracing (round-5 proven form, verbatim) ----
    bool  unf_s = m0, unf_e = m0;
    float acc_s = nearv, acc_e = farv;
    float next_s = unf_s ? sdfq(acc_s, trcd, cam2) : 0.0f;
    float next_e = unf_e ? sdfq(acc_e, trcd, cam2) : 0.0f;

    #pragma unroll 1
    for (int i = 0; i < TRACE_ITERS; ++i) {
        float cur_s = unf_s ? next_s : 0.0f;
        cur_s = (cur_s <= SDF_THR) ? 0.0f : cur_s;
        float cur_e = unf_e ? next_e : 0.0f;
        cur_e = (cur_e <= SDF_THR) ? 0.0f : cur_e;
        unf_s = unf_s && (cur_s > SDF_THR);
        unf_e = unf_e && (cur_e > SDF_THR);
        acc_s += cur_s;
        acc_e -= cur_e;
        next_s = unf_s ? sdfq(acc_s, trcd, cam2) : 0.0f;
        next_e = unf_e ? sdfq(acc_e, trcd, cam2) : 0.0f;
        bool np_s = (next_s < 0.0f) || (rcd + acc_s > 0.0f);   // ray.pts = rcd + acc
        bool np_e = (next_e < 0.0f) || (rcd + acc_e < 0.0f);
        if (np_s) { acc_s -= 0.9f * cur_s; next_s = sdfq(acc_s, trcd, cam2); }
        if (np_e) { acc_e += 0.9f * cur_e; next_e = sdfq(acc_e, trcd, cam2); }
        unf_s = unf_s && (acc_s < acc_e);
        unf_e = unf_e && (acc_s < acc_e);
        if (!__any(unf_s || unf_e)) break;   // bit-exact: converged lanes are no-ops
    }
    // final mask refresh
    {
        float cur_s = unf_s ? next_s : 0.0f;
        cur_s = (cur_s <= SDF_THR) ? 0.0f : cur_s;
        unf_s = unf_s && (cur_s > SDF_THR);
    }

    // ---- defaults from trace ----
    bool  out_m = acc_s < acc_e;
    float out_d = acc_s;

    if (unf_s) {
        float smin = acc_s, dzr = acc_e - acc_s;        // dzr > 0 (unf implies acc_s < acc_e)
        float step99 = dzr * (1.0f / 99.0f);            // approx step, index estimation only
        bool fellback = false;

        // ---- (a) discrete argmin + any-negative decision: window around vertex ----
        float fkv = (-rcd - smin) / step99;             // fractional vertex index
        fkv = fminf(fmaxf(fkv, 0.0f), 99.0f);           // clamp (also absorbs inf/NaN)
        int kv = (int)fkv;
        float bq = 3.4e38f; float bkf = 0.0f;
        #pragma unroll
        for (int d = -2; d <= 3; ++d) {
            int k = min(max(kv + d, 0), 99);            // nondecreasing sequence of k
            float q = qat(zq(k, dzr, smin), trcd, cam2);
            bool better = q < bq;                       // strict -> first occurrence
            bq  = better ? q : bq;
            bkf = better ? (float)k : bkf;
        }

        if (fabsf(bq - 1.0f) <= QGUARD) {
            fellback = true;                            // decision inside guard band
        } else if (bq > 1.0f) {
            // no negative sample anywhere (convexity + guard): min-sdf point
            out_d = zq((int)bkf, dzr, smin);
            out_m = false;
        } else {
            // negatives exist; find FIRST k with computed q < 1
            int kneg = 1000;
            float q0 = qat(smin, trcd, cam2);           // z_0 == smin exactly
            if (q0 < 1.0f) {
                kneg = 0;
            } else {
                float disc = fmaf(rcd, rcd, 1.0f - cam2);
                float zroot = -rcd - sqrtf(fmaxf(disc, 0.0f));   // left root of q=1
                float fk = (zroot - smin) / step99;
                fk = fminf(fmaxf(fk, -8.0f), 108.0f);
                int ka = (int)ceilf(fk);
                #pragma unroll
                for (int d = -3; d <= 3; ++d) {
                    int k = min(max(ka + d, 1), 99);    // nondecreasing sequence
                    float q = qat(zq(k, dzr, smin), trcd, cam2);
                    kneg = (q < 1.0f) ? min(kneg, k) : kneg;
                }
                if (kneg == 1000) {
                    fellback = true;                    // analytic index off -> rescan
                } else {
                    // verify contiguity: left neighbor clearly positive
                    float qprev = qat(zq(kneg - 1, dzr, smin), trcd, cam2);
                    if (!(qprev >= 1.0f + QGUARD)) fellback = true;
                }
            }
            if (!fellback) {
                int klo = max(kneg - 1, 0);
                float lo = zq(klo, dzr, smin);
                float hi = zq(kneg, dzr, smin);
                #pragma unroll
                for (int it = 0; it < N_ROOTFIND; ++it) {
                    float mid = 0.5f * (lo + hi);
                    float qm  = qat(mid, trcd, cam2);
                    bool go_lo = qm > 1.0f;             // sdf(mid) > 0
                    lo = go_lo ? mid : lo;
                    hi = go_lo ? hi : mid;
                }
                out_d = 0.5f * (lo + hi);
                out_m = true;
            }
        }

        if (fellback) {
            // ---- bit-exact full scan (round-5 sampler, verbatim) ----
            float qmin[4] = {3.4e38f, 3.4e38f, 3.4e38f, 3.4e38f};
            float fkq[4]  = {0.0f, 0.0f, 0.0f, 0.0f};
            float fneg[4] = {1e9f, 1e9f, 1e9f, 1e9f};
            #pragma unroll
            for (int k = 0; k < N_STEPS; ++k) {
                int j = k & 3;
                float z = zq(k, dzr, smin);             // div99(k) folds to a constant
                float q = qat(z, trcd, cam2);
                float fk = (float)k;
                fneg[j] = fminf(fneg[j], (q < 1.0f) ? fk : 1e9f);
                if (q < qmin[j]) { qmin[j] = q; fkq[j] = fk; }
            }
            float kneg_f = fminf(fminf(fneg[0], fneg[1]), fminf(fneg[2], fneg[3]));
            float bq2 = qmin[0], bk2 = fkq[0];
            #pragma unroll
            for (int j = 1; j < 4; ++j) {
                bool better = (qmin[j] < bq2) || ((qmin[j] == bq2) && (fkq[j] < bk2));
                bq2 = better ? qmin[j] : bq2;
                bk2 = better ? fkq[j]  : bk2;
            }
            if (kneg_f < 1e8f) {
                int kneg = (int)kneg_f;
                int klo  = (kneg - 1 > 0) ? (kneg - 1) : 0;
                float lo = zq(klo,  dzr, smin);
                float hi = zq(kneg, dzr, smin);
                #pragma unroll
                for (int it = 0; it < N_ROOTFIND; ++it) {
                    float mid = 0.5f * (lo + hi);
                    float qm  = qat(mid, trcd, cam2);
                    bool go_lo = qm > 1.0f;
                    lo = go_lo ? mid : lo;
                    hi = go_lo ? hi : mid;
                }
                out_d = 0.5f * (lo + hi);
                out_m = true;
            } else {
                out_d = zq((int)bk2, dzr, smin);
                out_m = false;
            }
        }
    }

    // ---- outputs: pts [R,3] | net_obj [R] | acc_s [R] ----
    out[(size_t)gid * 3 + 0] = fmaf(out_d, rx, cx);
    out[(size_t)gid * 3 + 1] = fmaf(out_d, ry, cy);
    out[(size_t)gid * 3 + 2] = fmaf(out_d, rz, cz);
    out[(size_t)R * 3 + gid] = out_m ? 1.0f : 0.0f;
    out[(size_t)R * 4 + gid] = out_d;
}

extern "C" void kernel_launch(void* const* d_in, const int* in_sizes, int n_in,
                              void* d_out, int out_size, void* d_ws, size_t ws_size,
                              hipStream_t stream) {
    const float* cam = (const float*)d_in[0];
    const float* ray = (const float*)d_in[1];
    int B = in_sizes[0] / 3;
    int R = in_sizes[1] / 3;
    int N = R / B;
    int threads = 256;
    int blocks = (R + threads - 1) / threads;
    raytrace_kernel<<<blocks, threads, 0, stream>>>(cam, ray, (float*)d_out, N, R);
}